// Round 1
// baseline (87.016 us; speedup 1.0000x reference)
//
#include <hip/hip_runtime.h>

#define WDIM 512
#define HDIM 512
#define NEG_INF (-__builtin_inff())
#define THRESH 0.3f

// One thread processes 4 contiguous pixels (along the last/H axis).
// Block = 256 threads = 2 rows of 512 pixels. Grid = 32 images * 256 blocks.
__global__ __launch_bounds__(256) void ToBoxes_52158082843018_kernel(
    const float* __restrict__ hm, const float* __restrict__ sz,
    float* __restrict__ kp_out, float* __restrict__ out5)
{
    const int blk = blockIdx.x;
    const int b  = blk >> 8;        // 256 blocks per image
    const int ir = blk & 255;       // 2 rows per block
    const int tid = threadIdx.x;
    const int i = ir * 2 + (tid >> 7);     // row index (W axis)
    const int j = (tid & 127) << 2;        // col index (H axis), multiple of 4

    const float* row = hm + ((size_t)b * WDIM + i) * HDIM;

    float c[6], u[6], d[6];

    // center row: cols j-1 .. j+4
    {
        float4 v = *reinterpret_cast<const float4*>(row + j);
        c[1] = v.x; c[2] = v.y; c[3] = v.z; c[4] = v.w;
        c[0] = (j > 0)          ? row[j - 1] : NEG_INF;
        c[5] = (j + 4 < HDIM)   ? row[j + 4] : NEG_INF;
    }
    // row above
    if (i > 0) {
        const float* ru = row - HDIM;
        float4 v = *reinterpret_cast<const float4*>(ru + j);
        u[1] = v.x; u[2] = v.y; u[3] = v.z; u[4] = v.w;
        u[0] = (j > 0)          ? ru[j - 1] : NEG_INF;
        u[5] = (j + 4 < HDIM)   ? ru[j + 4] : NEG_INF;
    } else {
        #pragma unroll
        for (int k = 0; k < 6; ++k) u[k] = NEG_INF;
    }
    // row below
    if (i < WDIM - 1) {
        const float* rd = row + HDIM;
        float4 v = *reinterpret_cast<const float4*>(rd + j);
        d[1] = v.x; d[2] = v.y; d[3] = v.z; d[4] = v.w;
        d[0] = (j > 0)          ? rd[j - 1] : NEG_INF;
        d[5] = (j + 4 < HDIM)   ? rd[j + 4] : NEG_INF;
    } else {
        #pragma unroll
        for (int k = 0; k < 6; ++k) d[k] = NEG_INF;
    }

    // sizes: (B, 2, W, H)
    const float* szb = sz + (size_t)b * 2 * WDIM * HDIM + (size_t)i * HDIM;
    float4 wv = *reinterpret_cast<const float4*>(szb + j);
    float4 hv = *reinterpret_cast<const float4*>(szb + (size_t)WDIM * HDIM + j);
    const float wsz[4] = { wv.x, wv.y, wv.z, wv.w };
    const float hsz[4] = { hv.x, hv.y, hv.z, hv.w };

    const float cxv = (float)i / (float)WDIM;

    float kpv[4];
    float o[20];
    #pragma unroll
    for (int k = 0; k < 4; ++k) {
        const float v = c[k + 1];
        // 9-way max over the (padded) 3x3 neighborhood — includes v itself
        float m = fmaxf(u[k], u[k + 1]);
        m = fmaxf(m, u[k + 2]);
        m = fmaxf(m, c[k]);
        m = fmaxf(m, c[k + 1]);
        m = fmaxf(m, c[k + 2]);
        m = fmaxf(m, d[k]);
        m = fmaxf(m, d[k + 1]);
        m = fmaxf(m, d[k + 2]);
        const bool keep = (m == v) && (v > THRESH);
        kpv[k] = keep ? 1.0f : 0.0f;
        const float cyv = (float)(j + k) / (float)HDIM;
        o[k * 5 + 0] = keep ? v    : 0.0f;
        o[k * 5 + 1] = keep ? cxv  : 0.0f;
        o[k * 5 + 2] = keep ? cyv  : 0.0f;
        o[k * 5 + 3] = keep ? wsz[k] : 0.0f;
        o[k * 5 + 4] = keep ? hsz[k] : 0.0f;
    }

    const size_t pix = ((size_t)b * WDIM + i) * HDIM + j;
    *reinterpret_cast<float4*>(kp_out + pix) = make_float4(kpv[0], kpv[1], kpv[2], kpv[3]);

    // 20 consecutive floats per thread; pix*5*4 bytes is 80-byte aligned
    float* op = out5 + pix * 5;
    #pragma unroll
    for (int q = 0; q < 5; ++q)
        *reinterpret_cast<float4*>(op + q * 4) =
            make_float4(o[q * 4], o[q * 4 + 1], o[q * 4 + 2], o[q * 4 + 3]);
}

extern "C" void kernel_launch(void* const* d_in, const int* in_sizes, int n_in,
                              void* d_out, int out_size, void* d_ws, size_t ws_size,
                              hipStream_t stream) {
    const float* hm = (const float*)d_in[0];   // (32,1,512,512)
    const float* sz = (const float*)d_in[1];   // (32,2,512,512)
    float* out  = (float*)d_out;
    float* kp   = out;                                   // (32,512,512) as 0/1 floats
    float* out5 = out + (size_t)32 * 512 * 512;          // (32,512,512,5)

    const int blocks = 32 * 256;   // 2 rows per block
    ToBoxes_52158082843018_kernel<<<blocks, 256, 0, stream>>>(hm, sz, kp, out5);
}

// Round 2
// 75.256 us; speedup vs baseline: 1.1563x; 1.1563x over previous
//
#include <hip/hip_runtime.h>

#define WDIM 512
#define HDIM 512
#define NEG_INF (-__builtin_inff())
#define THRESH 0.3f

// One thread computes 4 contiguous pixels (along last axis).
// Block = 256 threads = 2 rows. Grid = 32 images * 256 blocks = 8192.
// out5 (167 MB of the writes) is staged through LDS so global stores are
// fully coalesced; direct per-thread stores were 80B-stride scattered.
__global__ __launch_bounds__(256) void ToBoxes_52158082843018_kernel(
    const float* __restrict__ hm, const float* __restrict__ sz,
    float* __restrict__ kp_out, float* __restrict__ out5)
{
    // 21 floats per thread (stride 21 is coprime with 32 banks -> conflict-free)
    __shared__ float lds[256 * 21];

    // XCD-contiguous remap: blocks [x*1024,(x+1)*1024) run on XCD x,
    // so halo rows shared by adjacent blocks hit the same per-XCD L2.
    const int orig = blockIdx.x;
    const int blk  = (orig & 7) * 1024 + (orig >> 3);

    const int b   = blk >> 8;        // 256 blocks per image
    const int ir  = blk & 255;       // 2 rows per block
    const int tid = threadIdx.x;
    const int i = ir * 2 + (tid >> 7);     // row index (W axis)
    const int j = (tid & 127) << 2;        // col index (H axis), multiple of 4

    const float* row = hm + ((size_t)b * WDIM + i) * HDIM;

    float c[6], u[6], d[6];

    {
        float4 v = *reinterpret_cast<const float4*>(row + j);
        c[1] = v.x; c[2] = v.y; c[3] = v.z; c[4] = v.w;
        c[0] = (j > 0)        ? row[j - 1] : NEG_INF;
        c[5] = (j + 4 < HDIM) ? row[j + 4] : NEG_INF;
    }
    if (i > 0) {
        const float* ru = row - HDIM;
        float4 v = *reinterpret_cast<const float4*>(ru + j);
        u[1] = v.x; u[2] = v.y; u[3] = v.z; u[4] = v.w;
        u[0] = (j > 0)        ? ru[j - 1] : NEG_INF;
        u[5] = (j + 4 < HDIM) ? ru[j + 4] : NEG_INF;
    } else {
        #pragma unroll
        for (int k = 0; k < 6; ++k) u[k] = NEG_INF;
    }
    if (i < WDIM - 1) {
        const float* rd = row + HDIM;
        float4 v = *reinterpret_cast<const float4*>(rd + j);
        d[1] = v.x; d[2] = v.y; d[3] = v.z; d[4] = v.w;
        d[0] = (j > 0)        ? rd[j - 1] : NEG_INF;
        d[5] = (j + 4 < HDIM) ? rd[j + 4] : NEG_INF;
    } else {
        #pragma unroll
        for (int k = 0; k < 6; ++k) d[k] = NEG_INF;
    }

    // sizes: (B, 2, W, H)
    const float* szb = sz + (size_t)b * 2 * WDIM * HDIM + (size_t)i * HDIM;
    float4 wv = *reinterpret_cast<const float4*>(szb + j);
    float4 hv = *reinterpret_cast<const float4*>(szb + (size_t)WDIM * HDIM + j);
    const float wsz[4] = { wv.x, wv.y, wv.z, wv.w };
    const float hsz[4] = { hv.x, hv.y, hv.z, hv.w };

    const float cxv = (float)i / (float)WDIM;

    float kpv[4];
    float o[20];
    #pragma unroll
    for (int k = 0; k < 4; ++k) {
        const float v = c[k + 1];
        float m = fmaxf(u[k], u[k + 1]);
        m = fmaxf(m, u[k + 2]);
        m = fmaxf(m, c[k]);
        m = fmaxf(m, c[k + 1]);
        m = fmaxf(m, c[k + 2]);
        m = fmaxf(m, d[k]);
        m = fmaxf(m, d[k + 1]);
        m = fmaxf(m, d[k + 2]);
        const bool keep = (m == v) && (v > THRESH);
        kpv[k] = keep ? 1.0f : 0.0f;
        const float cyv = (float)(j + k) / (float)HDIM;
        o[k * 5 + 0] = keep ? v      : 0.0f;
        o[k * 5 + 1] = keep ? cxv    : 0.0f;
        o[k * 5 + 2] = keep ? cyv    : 0.0f;
        o[k * 5 + 3] = keep ? wsz[k] : 0.0f;
        o[k * 5 + 4] = keep ? hsz[k] : 0.0f;
    }

    // kp: already coalesced (16B/lane, contiguous across lanes)
    const size_t pix = ((size_t)b * WDIM + i) * HDIM + j;
    *reinterpret_cast<float4*>(kp_out + pix) = make_float4(kpv[0], kpv[1], kpv[2], kpv[3]);

    // stage out5 in LDS: flat element m lives at lds[m + m/20]
    float* myl = lds + tid * 21;
    #pragma unroll
    for (int e = 0; e < 20; ++e) myl[e] = o[e];
    __syncthreads();

    // block's out5 region: 2 rows * 512 px * 5 ch = 5120 contiguous floats
    float* op = out5 + ((size_t)b * WDIM + (size_t)(ir * 2)) * HDIM * 5;
    #pragma unroll
    for (int k = 0; k < 5; ++k) {
        const int m = k * 1024 + (tid << 2);
        float4 vv;
        vv.x = lds[m     + (m    ) / 20];
        vv.y = lds[m + 1 + (m + 1) / 20];
        vv.z = lds[m + 2 + (m + 2) / 20];
        vv.w = lds[m + 3 + (m + 3) / 20];
        *reinterpret_cast<float4*>(op + m) = vv;   // lane stride 16B: coalesced
    }
}

extern "C" void kernel_launch(void* const* d_in, const int* in_sizes, int n_in,
                              void* d_out, int out_size, void* d_ws, size_t ws_size,
                              hipStream_t stream) {
    const float* hm = (const float*)d_in[0];   // (32,1,512,512)
    const float* sz = (const float*)d_in[1];   // (32,2,512,512)
    float* out  = (float*)d_out;
    float* kp   = out;                                   // (32,512,512) as 0/1 floats
    float* out5 = out + (size_t)32 * 512 * 512;          // (32,512,512,5)

    const int blocks = 32 * 256;
    ToBoxes_52158082843018_kernel<<<blocks, 256, 0, stream>>>(hm, sz, kp, out5);
}

// Round 3
// 60.581 us; speedup vs baseline: 1.4364x; 1.2422x over previous
//
#include <hip/hip_runtime.h>

typedef float v4f __attribute__((ext_vector_type(4)));

#define WDIM 512
#define HDIM 512
#define NEG_INF (-__builtin_inff())
#define THRESH 0.3f

// One thread computes 4 contiguous pixels (last axis). Block = 256 threads
// = 2 rows. Grid = 32 images * 256 blocks = 8192.
// out5 staged through flat LDS (pure b128 both sides, ~2-way banks = free),
// then stored coalesced + nontemporal. sizes loaded nontemporal (read-once),
// hm loads stay cached (halo reuse in per-XCD L2).
__global__ __launch_bounds__(256) void ToBoxes_52158082843018_kernel(
    const float* __restrict__ hm, const float* __restrict__ sz,
    float* __restrict__ kp_out, float* __restrict__ out5)
{
    __shared__ float lds[5120];   // 2 rows * 512 px * 5 ch, flat

    // XCD-contiguous remap: blocks [x*1024,(x+1)*1024) -> XCD x, so halo
    // rows shared by adjacent blocks hit the same per-XCD L2. 8192 % 8 == 0.
    const int orig = blockIdx.x;
    const int blk  = (orig & 7) * 1024 + (orig >> 3);

    const int b   = blk >> 8;        // 256 blocks per image
    const int ir  = blk & 255;       // 2 rows per block
    const int tid = threadIdx.x;
    const int i = ir * 2 + (tid >> 7);     // row (W axis)
    const int j = (tid & 127) << 2;        // col (H axis), multiple of 4

    const float* row = hm + ((size_t)b * WDIM + i) * HDIM;

    float c[6], u[6], d[6];

    {
        float4 v = *reinterpret_cast<const float4*>(row + j);
        c[1] = v.x; c[2] = v.y; c[3] = v.z; c[4] = v.w;
        c[0] = (j > 0)        ? row[j - 1] : NEG_INF;
        c[5] = (j + 4 < HDIM) ? row[j + 4] : NEG_INF;
    }
    if (i > 0) {
        const float* ru = row - HDIM;
        float4 v = *reinterpret_cast<const float4*>(ru + j);
        u[1] = v.x; u[2] = v.y; u[3] = v.z; u[4] = v.w;
        u[0] = (j > 0)        ? ru[j - 1] : NEG_INF;
        u[5] = (j + 4 < HDIM) ? ru[j + 4] : NEG_INF;
    } else {
        #pragma unroll
        for (int k = 0; k < 6; ++k) u[k] = NEG_INF;
    }
    if (i < WDIM - 1) {
        const float* rd = row + HDIM;
        float4 v = *reinterpret_cast<const float4*>(rd + j);
        d[1] = v.x; d[2] = v.y; d[3] = v.z; d[4] = v.w;
        d[0] = (j > 0)        ? rd[j - 1] : NEG_INF;
        d[5] = (j + 4 < HDIM) ? rd[j + 4] : NEG_INF;
    } else {
        #pragma unroll
        for (int k = 0; k < 6; ++k) d[k] = NEG_INF;
    }

    // sizes: (B, 2, W, H) — read-once, nontemporal
    const float* szb = sz + (size_t)b * 2 * WDIM * HDIM + (size_t)i * HDIM;
    v4f wv = __builtin_nontemporal_load(reinterpret_cast<const v4f*>(szb + j));
    v4f hv = __builtin_nontemporal_load(
        reinterpret_cast<const v4f*>(szb + (size_t)WDIM * HDIM + j));
    const float wsz[4] = { wv.x, wv.y, wv.z, wv.w };
    const float hsz[4] = { hv.x, hv.y, hv.z, hv.w };

    const float cxv = (float)i / (float)WDIM;

    float kpv[4];
    float o[20];
    #pragma unroll
    for (int k = 0; k < 4; ++k) {
        const float v = c[k + 1];
        float m = fmaxf(u[k], u[k + 1]);
        m = fmaxf(m, u[k + 2]);
        m = fmaxf(m, c[k]);
        m = fmaxf(m, c[k + 1]);
        m = fmaxf(m, c[k + 2]);
        m = fmaxf(m, d[k]);
        m = fmaxf(m, d[k + 1]);
        m = fmaxf(m, d[k + 2]);
        const bool keep = (m == v) && (v > THRESH);
        kpv[k] = keep ? 1.0f : 0.0f;
        const float cyv = (float)(j + k) / (float)HDIM;
        o[k * 5 + 0] = keep ? v      : 0.0f;
        o[k * 5 + 1] = keep ? cxv    : 0.0f;
        o[k * 5 + 2] = keep ? cyv    : 0.0f;
        o[k * 5 + 3] = keep ? wsz[k] : 0.0f;
        o[k * 5 + 4] = keep ? hsz[k] : 0.0f;
    }

    // kp: coalesced, write-once -> nontemporal
    const size_t pix = ((size_t)b * WDIM + i) * HDIM + j;
    v4f kv = { kpv[0], kpv[1], kpv[2], kpv[3] };
    __builtin_nontemporal_store(kv, reinterpret_cast<v4f*>(kp_out + pix));

    // stage out5 flat in LDS: thread t owns floats [20t, 20t+20)
    // write: ds_write_b128 at byte 80t+16q -> start banks (20l+4q)%32, 2-way
    #pragma unroll
    for (int q = 0; q < 5; ++q) {
        v4f t = { o[4 * q], o[4 * q + 1], o[4 * q + 2], o[4 * q + 3] };
        *reinterpret_cast<v4f*>(&lds[tid * 20 + q * 4]) = t;
    }
    __syncthreads();

    // block's out5 region: 5120 contiguous floats; read b128 at 16*(k*256+tid)
    // -> start banks 4l%32, 2-way. Store coalesced (16B/lane) + nontemporal.
    float* op = out5 + ((size_t)b * WDIM + (size_t)(ir * 2)) * HDIM * 5;
    #pragma unroll
    for (int k = 0; k < 5; ++k) {
        const int m = k * 1024 + (tid << 2);
        v4f vv = *reinterpret_cast<const v4f*>(&lds[m]);
        __builtin_nontemporal_store(vv, reinterpret_cast<v4f*>(op + m));
    }
}

extern "C" void kernel_launch(void* const* d_in, const int* in_sizes, int n_in,
                              void* d_out, int out_size, void* d_ws, size_t ws_size,
                              hipStream_t stream) {
    const float* hm = (const float*)d_in[0];   // (32,1,512,512)
    const float* sz = (const float*)d_in[1];   // (32,2,512,512)
    float* out  = (float*)d_out;
    float* kp   = out;                                   // (32,512,512) as 0/1
    float* out5 = out + (size_t)32 * 512 * 512;          // (32,512,512,5)

    const int blocks = 32 * 256;
    ToBoxes_52158082843018_kernel<<<blocks, 256, 0, stream>>>(hm, sz, kp, out5);
}

// Round 4
// 56.199 us; speedup vs baseline: 1.5484x; 1.0780x over previous
//
#include <hip/hip_runtime.h>

typedef float v4f __attribute__((ext_vector_type(4)));

#define WDIM 512
#define HDIM 512
#define NEG_INF (-__builtin_inff())
#define THRESH 0.3f
#define INV512 0.001953125f   // 1/512, exact; x*INV512 == x/512 bit-exact (pow2)

// One thread computes 4 contiguous pixels (last axis). Block = 256 threads
// = 2 rows. Grid = 32 images * 256 blocks = 8192.
// Halo columns come from neighbor lanes via shfl (1-lane predicated edge
// loads at wave boundaries) instead of full-wave redundant dword loads.
// out5 staged through flat LDS (b128 both sides, 2-way banks = free), then
// stored coalesced + nontemporal. sizes loaded nontemporal (read-once),
// hm loads stay cached (halo reuse in per-XCD L2).
__global__ __launch_bounds__(256) void ToBoxes_52158082843018_kernel(
    const float* __restrict__ hm, const float* __restrict__ sz,
    float* __restrict__ kp_out, float* __restrict__ out5)
{
    __shared__ float lds[5120];   // 2 rows * 512 px * 5 ch, flat

    // XCD-contiguous remap: blocks [x*1024,(x+1)*1024) -> XCD x, so halo
    // rows shared by adjacent blocks hit the same per-XCD L2. 8192 % 8 == 0.
    const int orig = blockIdx.x;
    const int blk  = (orig & 7) * 1024 + (orig >> 3);

    const int b    = blk >> 8;       // 256 blocks per image
    const int ir   = blk & 255;      // 2 rows per block
    const int tid  = threadIdx.x;
    const int lane = tid & 63;
    const int i = ir * 2 + (tid >> 7);     // row (W axis)
    const int j = (tid & 127) << 2;        // col (H axis), multiple of 4

    // issue the read-once NT sizes loads first (longest latency path)
    const float* szb = sz + (size_t)b * 2 * WDIM * HDIM + (size_t)i * HDIM;
    v4f wv = __builtin_nontemporal_load(reinterpret_cast<const v4f*>(szb + j));
    v4f hv = __builtin_nontemporal_load(
        reinterpret_cast<const v4f*>(szb + (size_t)WDIM * HDIM + j));

    const float* row = hm + ((size_t)b * WDIM + i) * HDIM;

    float c[6], u[6], d[6];

    // load 6 halo-extended columns of one row: vector load + lane shuffles;
    // only lanes 0/63 do a (predicated, 1-lane) edge load.
    auto load_row6 = [&](const float* rp, float* dst) {
        float4 v = *reinterpret_cast<const float4*>(rp + j);
        dst[1] = v.x; dst[2] = v.y; dst[3] = v.z; dst[4] = v.w;
        float lft = __shfl_up(v.w, 1);    // lane l-1's col j-1... = rp[j-1]
        float rgt = __shfl_down(v.x, 1);  // lane l+1's col j+4  = rp[j+4]
        if (lane == 0)  lft = (j > 0)        ? rp[j - 1] : NEG_INF;
        if (lane == 63) rgt = (j + 4 < HDIM) ? rp[j + 4] : NEG_INF;
        dst[0] = lft; dst[5] = rgt;
    };

    load_row6(row, c);
    if (i > 0) {                       // wave-uniform branch (i uniform in wave)
        load_row6(row - HDIM, u);
    } else {
        #pragma unroll
        for (int k = 0; k < 6; ++k) u[k] = NEG_INF;
    }
    if (i < WDIM - 1) {
        load_row6(row + HDIM, d);
    } else {
        #pragma unroll
        for (int k = 0; k < 6; ++k) d[k] = NEG_INF;
    }

    const float wsz[4] = { wv.x, wv.y, wv.z, wv.w };
    const float hsz[4] = { hv.x, hv.y, hv.z, hv.w };
    const float cxv = (float)i * INV512;

    float kpv[4];
    float o[20];
    #pragma unroll
    for (int k = 0; k < 4; ++k) {
        const float v = c[k + 1];
        float m = fmaxf(u[k], u[k + 1]);
        m = fmaxf(m, u[k + 2]);
        m = fmaxf(m, c[k]);
        m = fmaxf(m, c[k + 1]);
        m = fmaxf(m, c[k + 2]);
        m = fmaxf(m, d[k]);
        m = fmaxf(m, d[k + 1]);
        m = fmaxf(m, d[k + 2]);
        const bool keep = (m == v) && (v > THRESH);
        kpv[k] = keep ? 1.0f : 0.0f;
        const float cyv = (float)(j + k) * INV512;
        o[k * 5 + 0] = keep ? v      : 0.0f;
        o[k * 5 + 1] = keep ? cxv    : 0.0f;
        o[k * 5 + 2] = keep ? cyv    : 0.0f;
        o[k * 5 + 3] = keep ? wsz[k] : 0.0f;
        o[k * 5 + 4] = keep ? hsz[k] : 0.0f;
    }

    // kp: coalesced, write-once -> nontemporal
    const size_t pix = ((size_t)b * WDIM + i) * HDIM + j;
    v4f kv = { kpv[0], kpv[1], kpv[2], kpv[3] };
    __builtin_nontemporal_store(kv, reinterpret_cast<v4f*>(kp_out + pix));

    // stage out5 flat in LDS: thread t owns floats [20t, 20t+20)
    #pragma unroll
    for (int q = 0; q < 5; ++q) {
        v4f t = { o[4 * q], o[4 * q + 1], o[4 * q + 2], o[4 * q + 3] };
        *reinterpret_cast<v4f*>(&lds[tid * 20 + q * 4]) = t;
    }
    __syncthreads();

    // block's out5 region: 5120 contiguous floats; coalesced NT b128 stores
    float* op = out5 + ((size_t)b * WDIM + (size_t)(ir * 2)) * HDIM * 5;
    #pragma unroll
    for (int k = 0; k < 5; ++k) {
        const int m = k * 1024 + (tid << 2);
        v4f vv = *reinterpret_cast<const v4f*>(&lds[m]);
        __builtin_nontemporal_store(vv, reinterpret_cast<v4f*>(op + m));
    }
}

extern "C" void kernel_launch(void* const* d_in, const int* in_sizes, int n_in,
                              void* d_out, int out_size, void* d_ws, size_t ws_size,
                              hipStream_t stream) {
    const float* hm = (const float*)d_in[0];   // (32,1,512,512)
    const float* sz = (const float*)d_in[1];   // (32,2,512,512)
    float* out  = (float*)d_out;
    float* kp   = out;                                   // (32,512,512) as 0/1
    float* out5 = out + (size_t)32 * 512 * 512;          // (32,512,512,5)

    const int blocks = 32 * 256;
    ToBoxes_52158082843018_kernel<<<blocks, 256, 0, stream>>>(hm, sz, kp, out5);
}